// Round 1
// baseline (887.996 us; speedup 1.0000x reference)
//
#include <hip/hip_runtime.h>

// BoxFilter: separable 9x9 depthwise box filter, fp32 NHWC.
// x: (4,1080,1920,16), wy: (9,1,1,16), wx: (1,9,1,16) -> out: (4,1072,1912,16)

#define RR 4
#define KK 9
#define BB 4
#define HH 1080
#define WW 1920
#define CC 16
#define H_OUT (HH - 2 * RR) // 1072
#define W_OUT (WW - 2 * RR) // 1912
#define TW 128              // output columns per block
#define TWH (TW + 2 * RR)   // 136 input pixels staged per row
#define NBW ((W_OUT + TW - 1) / TW) // 15
#define SEG 12
#define SH ((H_OUT + SEG - 1) / SEG) // 90 output rows per segment
#define NTHREADS 512
#define NQ_MAX (TWH * 4) // 544 float4 quads per staged row

__device__ __forceinline__ float4 f4_add(float4 a, float4 b) {
    return make_float4(a.x + b.x, a.y + b.y, a.z + b.z, a.w + b.w);
}
__device__ __forceinline__ float4 f4_sub(float4 a, float4 b) {
    return make_float4(a.x - b.x, a.y - b.y, a.z - b.z, a.w - b.w);
}

__global__ __launch_bounds__(NTHREADS, 4) // 4 waves/EU -> 2 blocks/CU, VGPR<=128
void box_filter_kernel(const float* __restrict__ x,
                       const float* __restrict__ wy,
                       const float* __restrict__ wx,
                       float* __restrict__ out) {
    __shared__ float lds[TWH * CC]; // 8704 B: one input row segment

    const int tid = threadIdx.x;
    const int wl  = tid >> 2;        // 0..127 : output column within tile
    const int c4  = (tid & 3) * 4;   // channel quad offset: 0,4,8,12

    const int bw  = blockIdx.x;      // W tile
    const int seg = blockIdx.y;      // H segment
    const int b   = blockIdx.z;      // batch

    const int w0  = bw * TW;
    const int hy0 = seg * SH;
    const int hy1 = min(hy0 + SH, H_OUT);
    const int n_rows = hy1 - hy0 + 2 * RR; // input rows this block consumes

    const int valid_px = min(TWH, WW - w0); // 136, or 128 for last tile
    const int nq = valid_px * 4;            // float4 quads per row (512 or 544)

    // Per-channel scale: taps are uniform (1/K each pass) -> fold into one mul.
    float4 sc;
    sc.x = wy[c4 + 0] * wx[c4 + 0];
    sc.y = wy[c4 + 1] * wx[c4 + 1];
    sc.z = wy[c4 + 2] * wx[c4 + 2];
    sc.w = wy[c4 + 3] * wx[c4 + 3];

    float4* ldsq = (float4*)lds;
    const int q0 = tid;                 // always < nq (nq >= 512)
    const int q1 = tid + NTHREADS;      // valid only if < nq
    const bool has_q1 = (q1 < nq);

    // Prefetch input row 0 of this segment into registers.
    const float4* xq = (const float4*)(x + ((b * HH + hy0) * WW + w0) * CC);
    float4 a0 = xq[q0];
    float4 a1 = make_float4(0.f, 0.f, 0.f, 0.f);
    if (has_q1) a1 = xq[q1];

    float4 ring[KK]; // hsum history; static indices via unroll-by-K
    float4 vsum = make_float4(0.f, 0.f, 0.f, 0.f);

    const int wo = w0 + wl;
    const bool do_store = (wo < W_OUT);

    for (int rbase = 0; rbase < n_rows; rbase += KK) {
#pragma unroll
        for (int j = 0; j < KK; ++j) {
            const int r = rbase + j;
            if (r < n_rows) {
                // Publish the prefetched row r to LDS.
                __syncthreads(); // all waves done reading row r-1
                ldsq[q0] = a0;
                if (has_q1) ldsq[q1] = a1;
                __syncthreads();

                // Issue prefetch of row r+1 (lands before next LDS write).
                const int rn = r + 1;
                if (rn < n_rows) {
                    const float4* xq2 =
                        (const float4*)(x + ((b * HH + hy0 + rn) * WW + w0) * CC);
                    a0 = xq2[q0];
                    if (has_q1) a1 = xq2[q1];
                }

                // Horizontal 9-tap sum from LDS (ds_read_b128 x9).
                const float* base = lds + wl * CC + c4;
                float4 hs = *(const float4*)(base);
#pragma unroll
                for (int dw = 1; dw < KK; ++dw) {
                    hs = f4_add(hs, *(const float4*)(base + dw * CC));
                }

                // Vertical running sum over the last 9 rows.
                vsum = f4_add(vsum, hs);
                if (r >= KK) vsum = f4_sub(vsum, ring[j]); // ring[j] = hsum(r-9)
                ring[j] = hs;

                if (r >= 2 * RR && do_store) {
                    const int ho = hy0 + r - 2 * RR;
                    float4 o;
                    o.x = vsum.x * sc.x;
                    o.y = vsum.y * sc.y;
                    o.z = vsum.z * sc.z;
                    o.w = vsum.w * sc.w;
                    float* op = out + ((b * H_OUT + ho) * W_OUT + wo) * CC + c4;
                    *(float4*)op = o;
                }
            }
        }
    }
}

extern "C" void kernel_launch(void* const* d_in, const int* in_sizes, int n_in,
                              void* d_out, int out_size, void* d_ws, size_t ws_size,
                              hipStream_t stream) {
    const float* x  = (const float*)d_in[0];
    const float* wy = (const float*)d_in[1];
    const float* wx = (const float*)d_in[2];
    float* out = (float*)d_out;

    dim3 grid(NBW, SEG, BB); // (15, 12, 4) = 720 blocks
    box_filter_kernel<<<grid, NTHREADS, 0, stream>>>(x, wy, wx, out);
}